// Round 12
// baseline (56.587 us; speedup 1.0000x reference)
//
#include <hip/hip_runtime.h>
#include <stdint.h>

#define NB    64       // batch
#define KMAX  16
#define VV    32000    // vocab
#define DVV   10
#define HH    4096
#define NROWS (NB*KMAX)
#define EPSF  1e-8f
#define NQ    8000     // float4 groups per row (4*8000 = 32000)

typedef float floatx4 __attribute__((ext_vector_type(4)));

// ---------------- Threefry-2x32 (exact JAX reference implementation) ----------------
__device__ __forceinline__ uint32_t rotl32(uint32_t v, int r) { return (v << r) | (v >> (32 - r)); }

__device__ __forceinline__ void tf2x32(uint32_t k0, uint32_t k1, uint32_t c0, uint32_t c1,
                                       uint32_t& o0, uint32_t& o1) {
    uint32_t ks2 = k0 ^ k1 ^ 0x1BD11BDAu;
    uint32_t x0 = c0 + k0, x1 = c1 + k1;
    const int RA[4] = {13, 15, 26, 6};
    const int RB[4] = {17, 29, 16, 24};
#pragma unroll
    for (int i = 0; i < 4; ++i) { x0 += x1; x1 = rotl32(x1, RA[i]); x1 ^= x0; }
    x0 += k1; x1 += ks2 + 1u;
#pragma unroll
    for (int i = 0; i < 4; ++i) { x0 += x1; x1 = rotl32(x1, RB[i]); x1 ^= x0; }
    x0 += ks2; x1 += k0 + 2u;
#pragma unroll
    for (int i = 0; i < 4; ++i) { x0 += x1; x1 = rotl32(x1, RA[i]); x1 ^= x0; }
    x0 += k0; x1 += k1 + 3u;
#pragma unroll
    for (int i = 0; i < 4; ++i) { x0 += x1; x1 = rotl32(x1, RB[i]); x1 ^= x0; }
    x0 += k1; x1 += ks2 + 4u;
#pragma unroll
    for (int i = 0; i < 4; ++i) { x0 += x1; x1 = rotl32(x1, RA[i]); x1 ^= x0; }
    x0 += ks2; x1 += k0 + 5u;
    o0 = x0; o1 = x1;
}

__device__ __forceinline__ float bits_to_u01(uint32_t bits) {
    uint32_t fb = (bits >> 9) | 0x3F800000u;
    return __uint_as_float(fb) - 1.0f;
}

__device__ __forceinline__ void nt_store4(float* p, float a, float b, float c, float d) {
    floatx4 v = {a, b, c, d};
    __builtin_nontemporal_store(v, (floatx4*)p);
}

// ------------- main: build p_cf_z (one block per row; x-seam via LDS) -------------
// Pass 1: ALIGNED float4 global loads of group q -> registers r[i] (warp rows
// transform here, once); only x-components go to LDS xflat[q] (group-indexed,
// stride-1, conflict-free). One barrier. Pass 2: ALIGNED 16B NT store of
// dst[4q+1..4q+4] = (r.y, r.z, r.w, xflat[q+1]) — both global streams aligned,
// zero unaligned LDS reads. Edges from the q==0 / q==NQ-1 threads' registers.
__global__ __launch_bounds__(1024) void cf_main_kernel(const float* __restrict__ p_z,
                                                       const int* __restrict__ k_vals,
                                                       float* __restrict__ out) {
    const int row = blockIdx.x;
    const int b = row >> 4, s = row & 15;
    const int tid = threadIdx.x;
    float* dst = out + 3 + (size_t)row * VV;

    __shared__ float xflat[NQ];        // 32 KB: x-component of each group
    __shared__ float red1[16];
    __shared__ int   s_src;
    __shared__ float s_itau;

    // ---- in-block setup (first 16 lanes; R7-proven) ----
    if (tid < 16) {
        const int t = tid;
        uint32_t a0, b0_, a1, b1_, a2, b2_, y0, y1;
        tf2x32(0u, 0u, 0u, 3u, a0, b0_);
        tf2x32(0u, 0u, 1u, 4u, a1, b1_);
        tf2x32(0u, 0u, 2u, 5u, a2, b2_);
        const uint32_t kdec0 = a0, kdec1 = a1;
        const uint32_t kperm0 = a2, kperm1 = b0_;
        const uint32_t ktau0 = b1_, ktau1 = b2_;

        const int k = k_vals[b];

        uint32_t bits;
        if (b < 32) { tf2x32(kdec0, kdec1, (uint32_t)b, (uint32_t)(b + 32), y0, y1); bits = y0; }
        else        { tf2x32(kdec0, kdec1, (uint32_t)(b - 32), (uint32_t)b, y0, y1); bits = y1; }
        const float u_dec = bits_to_u01(bits);
        const bool dp = (k > 1) && (u_dec < ((k >= 2) ? 0.5f : 0.0f));

        const int j = (b << 4) + t;
        uint32_t pb;
        if (j < 512) { tf2x32(kperm0, kperm1, (uint32_t)j, (uint32_t)(j + 512), y0, y1); pb = y0; }
        else         { tf2x32(kperm0, kperm1, (uint32_t)(j - 512), (uint32_t)j, y0, y1); pb = y1; }
        const float up = bits_to_u01(pb);

        const float INF = __int_as_float(0x7F800000);
        const float keyt = (t < k) ? up : INF;
        int r = 0;
#pragma unroll
        for (int tt = 0; tt < KMAX; ++tt) {
            float kt = __shfl(keyt, tt, 64);
            r += (kt < keyt) || (kt == keyt && tt < t);
        }

        if (s >= k)  { if (t == 0) { s_src = s; s_itau = 0.f; } }    // inactive: self-copy
        else if (dp) { if (r == s) { s_src = t; s_itau = 0.f; } }    // permuted: inverse perm
        else if (t == 0) {                                            // warp: tau for (b,s)
            const int js = (b << 4) + s;
            uint32_t tb;
            if (js < 512) { tf2x32(ktau0, ktau1, (uint32_t)js, (uint32_t)(js + 512), y0, y1); tb = y0; }
            else          { tf2x32(ktau0, ktau1, (uint32_t)(js - 512), (uint32_t)js, y0, y1); tb = y1; }
            const float tau = fmaxf(0.7f, bits_to_u01(tb) * 0.9f + 0.7f);
            s_src = -1; s_itau = 1.0f / tau;
        }
    }
    __syncthreads();

    const int src = s_src;
    const bool warp = (src < 0);
    const float it = s_itau;
    const float* sp = p_z + (size_t)((b << 4) + (warp ? s : src)) * VV;

    // ---- pass 1: aligned loads -> registers (+pow for warp rows); x -> LDS ----
    float4 r[8];
    float lsum = 0.f;
#pragma unroll
    for (int i = 0; i < 8; ++i) {
        const int q = tid + (i << 10);
        if (q < NQ) {
            float4 v = *(const float4*)(sp + (q << 2));
            if (warp) {
                v.x = exp2f(__log2f(fmaxf(v.x, EPSF)) * it);
                v.y = exp2f(__log2f(fmaxf(v.y, EPSF)) * it);
                v.z = exp2f(__log2f(fmaxf(v.z, EPSF)) * it);
                v.w = exp2f(__log2f(fmaxf(v.w, EPSF)) * it);
                lsum += v.x + v.y + v.z + v.w;
            }
            r[i] = v;
            xflat[q] = v.x;
        }
    }

    float scale = 1.0f;
    if (warp) {
        float t = lsum;
#pragma unroll
        for (int o = 32; o; o >>= 1) t += __shfl_down(t, o, 64);
        if ((tid & 63) == 0) red1[tid >> 6] = t;
        __syncthreads();
        if (tid < 64) {
            float u = (tid < 16) ? red1[tid] : 0.0f;
#pragma unroll
            for (int o = 8; o; o >>= 1) u += __shfl_down(u, o, 64);
            if (tid == 0) red1[0] = u;
        }
        __syncthreads();
        scale = 1.0f / red1[0];
    } else {
        __syncthreads();
    }

    // ---- pass 2: aligned NT stores; seam x from LDS ----
#pragma unroll
    for (int i = 0; i < 8; ++i) {
        const int q = tid + (i << 10);
        if (q < NQ - 1) {
            nt_store4(dst + (q << 2) + 1,
                      r[i].y * scale, r[i].z * scale, r[i].w * scale,
                      xflat[q + 1] * scale);
        } else if (q == NQ - 1) {
            dst[VV - 3] = r[i].y * scale;
            dst[VV - 2] = r[i].z * scale;
            dst[VV - 1] = r[i].w * scale;
        }
    }
    if (tid == 0) dst[0] = r[0].x * scale;
}

// ------------- per-batch reductions over h_ans (H=4096) -------------
__global__ __launch_bounds__(256) void rowred_kernel(const float* __restrict__ hr,
                                                     const float* __restrict__ hc,
                                                     float* __restrict__ cosb,
                                                     float* __restrict__ depb) {
    int b = blockIdx.x;
    const float4* r4 = (const float4*)(hr + (size_t)b * HH);
    const float4* c4 = (const float4*)(hc + (size_t)b * HH);
    float srr = 0.f, scc = 0.f, sxc = 0.f, sdd = 0.f;
    for (int i = threadIdx.x; i < HH / 4; i += 256) {
        float4 r = r4[i], c = c4[i];
        srr += r.x * r.x + r.y * r.y + r.z * r.z + r.w * r.w;
        scc += c.x * c.x + c.y * c.y + c.z * c.z + c.w * c.w;
        sxc += r.x * c.x + r.y * c.y + r.z * c.z + r.w * c.w;
        float dx = r.x - c.x, dy = r.y - c.y, dz = r.z - c.z, dw = r.w - c.w;
        sdd += dx * dx + dy * dy + dz * dz + dw * dw;
    }
#pragma unroll
    for (int o = 32; o; o >>= 1) {
        srr += __shfl_down(srr, o, 64);
        scc += __shfl_down(scc, o, 64);
        sxc += __shfl_down(sxc, o, 64);
        sdd += __shfl_down(sdd, o, 64);
    }
    __shared__ float red[4][4];
    int w = threadIdx.x >> 6;
    if ((threadIdx.x & 63) == 0) { red[w][0] = srr; red[w][1] = scc; red[w][2] = sxc; red[w][3] = sdd; }
    __syncthreads();
    if (threadIdx.x == 0) {
        float t0 = 0.f, t1 = 0.f, t2 = 0.f, t3 = 0.f;
        for (int i = 0; i < 4; ++i) { t0 += red[i][0]; t1 += red[i][1]; t2 += red[i][2]; t3 += red[i][3]; }
        float nr = fmaxf(sqrtf(t0), 1e-12f);
        float nc = fmaxf(sqrtf(t1), 1e-12f);
        cosb[b] = t2 / (nr * nc);
        depb[b] = sqrtf(t3);
    }
}

// ------------- JS divergence + final scalars -------------
__global__ void finalize_kernel(const float* __restrict__ dlr, const float* __restrict__ dlc,
                                const float* __restrict__ cosb, const float* __restrict__ depb,
                                float* __restrict__ out) {
    int b = threadIdx.x;  // 64 threads = 1 wave
    float lr[DVV], lc[DVV];
    float mr = -1e30f, mc = -1e30f;
#pragma unroll
    for (int v = 0; v < DVV; ++v) {
        lr[v] = dlr[b * DVV + v]; lc[v] = dlc[b * DVV + v];
        mr = fmaxf(mr, lr[v]); mc = fmaxf(mc, lc[v]);
    }
    float sr = 0.f, sc = 0.f;
#pragma unroll
    for (int v = 0; v < DVV; ++v) {
        lr[v] = expf(lr[v] - mr); sr += lr[v];
        lc[v] = expf(lc[v] - mc); sc += lc[v];
    }
    float js = 0.f;
#pragma unroll
    for (int v = 0; v < DVV; ++v) {
        float p = fmaxf(lr[v] / sr, EPSF);
        float q = fmaxf(lc[v] / sc, EPSF);
        float m = 0.5f * (p + q);
        float lm = logf(m);
        js += 0.5f * (p * (logf(p) - lm) + q * (logf(q) - lm));
    }
    float cs = cosb[b], dp = depb[b];
#pragma unroll
    for (int o = 32; o; o >>= 1) {
        js += __shfl_down(js, o, 64);
        cs += __shfl_down(cs, o, 64);
        dp += __shfl_down(dp, o, 64);
    }
    if (b == 0) {
        out[0] = logf(2.0f) - js * (1.0f / 64.0f);
        out[1] = cs * (1.0f / 64.0f) - 1.0f;
        out[2] = dp * (1.0f / 64.0f);
    }
}

extern "C" void kernel_launch(void* const* d_in, const int* in_sizes, int n_in,
                              void* d_out, int out_size, void* d_ws, size_t ws_size,
                              hipStream_t stream) {
    const float* p_z = (const float*)d_in[0];
    const float* dlr = (const float*)d_in[1];
    const float* dlc = (const float*)d_in[2];
    const float* hr  = (const float*)d_in[3];
    const float* hc  = (const float*)d_in[4];
    const int*   kv  = (const int*)d_in[5];
    float* out = (float*)d_out;

    float* cosb = (float*)d_ws;
    float* depb = cosb + NB;

    cf_main_kernel<<<NROWS, 1024, 0, stream>>>(p_z, kv, out);
    rowred_kernel<<<NB, 256, 0, stream>>>(hr, hc, cosb, depb);
    finalize_kernel<<<1, 64, 0, stream>>>(dlr, dlc, cosb, depb, out);
}